// Round 6
// baseline (241.202 us; speedup 1.0000x reference)
//
#include <hip/hip_runtime.h>
#include <hip/hip_bf16.h>
#include <math.h>

// Problem constants (match reference)
#define BB  32
#define SS  4096
#define VV  256
#define DD  256
#define CC  2
#define WIN 64
#define NW  64   // SS/WIN
#define WPB 4    // windows per main block
#define NGRP (NW / WPB)   // 16 groups

typedef unsigned short ushort_t;
typedef unsigned int   uint_t;
typedef __attribute__((ext_vector_type(8))) short short8;    // 8 bf16 (4 VGPRs)
typedef __attribute__((ext_vector_type(4))) float f32x4;

// Workspace layout (byte offsets). Total 573440 B.
#define WS_ATHI_B 0u          // ushort Athi[64][64]   8192  (A-op layout: [t][s])
#define WS_ATLO_B 8192u       // ushort Atlo[64][64]   8192
#define WS_GPK_B  16384u      // uint   gpk[256][256]  262144 (hi<<16 | lo per elem)
#define WS_W2HI_B 278528u     // ushort W2hi[256][256] 131072
#define WS_W2LO_B 409600u     // ushort W2lo[256][256] 131072
#define WS_POOL_B 540672u     // float  pool[32][256]  32768

__device__ __forceinline__ float fast_tanh(float v) {
  float e = __expf(2.0f * v);
  return 1.0f - __fdividef(2.0f, e + 1.0f);
}

// Truncation-based bf16 split: v ~= hi + lo with |err| <= 2^-17 * |v|.
__device__ __forceinline__ uint_t split_pack(float v) {
  uint_t b  = __float_as_uint(v);
  uint_t hi = b & 0xffff0000u;
  float  r  = v - __uint_as_float(hi);
  uint_t lo = __float_as_uint(r) >> 16;
  return hi | lo;
}

// Pack hi/lo halves of two packed u32 into bf16 pair dwords via v_perm.
__device__ __forceinline__ uint_t perm_hi(uint_t p0, uint_t p1) {
  return __builtin_amdgcn_perm(p1, p0, 0x07060302u);
}
__device__ __forceinline__ uint_t perm_lo(uint_t p0, uint_t p1) {
  return __builtin_amdgcn_perm(p1, p0, 0x05040100u);
}

union u4s8 { uint_t u[4]; short8 v; };

// Issue the 32 gather loads for one window into raw packed regs q[k0][nt][j].
__device__ __forceinline__ void issue_gather(
    const uint_t* __restrict__ gpk, int xvw, int dbase, int quad, int l16,
    uint_t (&q)[2][2][8])
{
  #pragma unroll
  for (int k0 = 0; k0 < 2; ++k0) {
    const int sl = k0 * 32 + quad * 8;
    int xs[8];
    #pragma unroll
    for (int j = 0; j < 8; ++j) xs[j] = __shfl(xvw, sl + j, 64);
    #pragma unroll
    for (int nt = 0; nt < 2; ++nt) {
      const int d = dbase + 16 * nt + l16;
      #pragma unroll
      for (int j = 0; j < 8; ++j) q[k0][nt][j] = gpk[xs[j] * DD + d];
    }
  }
}

// ---------------------------------------------------------------------------
// Prep grid (130 blocks):
//  blk 0       : attention matrix -> split bf16 planes Athi/Atlo ([t][s])
//  blk 1       : zero pooled accumulator
//  blk 2..65   : g = emb @ W1^T, 4 v-rows per block, packed-split into gpk
//  blk 66..129 : W2 -> split planes W2hi/W2lo, 4 c-rows per block
// ---------------------------------------------------------------------------
__global__ __launch_bounds__(256) void prep_kernel(
    const float* __restrict__ emb, const float* __restrict__ W1,
    const float* __restrict__ W2, char* __restrict__ ws)
{
  const int blk = blockIdx.x;
  const int tid = threadIdx.x;
  ushort_t* Athi = (ushort_t*)(ws + WS_ATHI_B);
  ushort_t* Atlo = (ushort_t*)(ws + WS_ATLO_B);
  uint_t*   gpk  = (uint_t*)  (ws + WS_GPK_B);
  ushort_t* W2hi = (ushort_t*)(ws + WS_W2HI_B);
  ushort_t* W2lo = (ushort_t*)(ws + WS_W2LO_B);
  float*    pool = (float*)   (ws + WS_POOL_B);

  if (blk == 0) {
    if (tid < WIN) {
      const int s = tid;
      const float omega = 60.0f * 2.0f * 3.14159265358979323846f / 4095.0f;
      float row[WIN];
      float sum = 0.0f;
      for (int t = 0; t < WIN; ++t) {
        float e = expf(cosf(omega * (float)(s - t)));
        row[t] = e;
        sum += e;
      }
      const float inv = 1.0f / sum;
      for (int t = 0; t < WIN; ++t) {
        uint_t pk = split_pack(row[t] * inv);
        Athi[t * WIN + s] = (ushort_t)(pk >> 16);
        Atlo[t * WIN + s] = (ushort_t)(pk & 0xffffu);
      }
    }
  } else if (blk == 1) {
    for (int i = tid; i < BB * DD; i += 256) pool[i] = 0.0f;
  } else if (blk < 66) {
    const int v0 = (blk - 2) * 4;
    __shared__ float er[4][DD];
    for (int i = tid; i < 4 * DD; i += 256) er[i >> 8][i & 255] = emb[v0 * DD + i];
    __syncthreads();
    float acc[4] = {0.0f, 0.0f, 0.0f, 0.0f};
    #pragma unroll 1
    for (int k0 = 0; k0 < DD; k0 += 64) {
      float4 wv[16];
      #pragma unroll
      for (int i = 0; i < 16; ++i) wv[i] = *(const float4*)(W1 + tid * DD + k0 + 4 * i);
      #pragma unroll
      for (int v = 0; v < 4; ++v) {
        float a = 0.0f;
        #pragma unroll
        for (int i = 0; i < 16; ++i) {
          float4 e = *(const float4*)(&er[v][k0 + 4 * i]);
          a += e.x * wv[i].x + e.y * wv[i].y + e.z * wv[i].z + e.w * wv[i].w;
        }
        acc[v] += a;
      }
    }
    #pragma unroll
    for (int v = 0; v < 4; ++v) gpk[(v0 + v) * DD + tid] = split_pack(acc[v]);
  } else {
    const int c0 = (blk - 66) * 4;
    #pragma unroll
    for (int i = 0; i < 4; ++i) {
      const int c = c0 + i;
      uint_t pk = split_pack(W2[c * DD + tid]);
      W2hi[c * DD + tid] = (ushort_t)(pk >> 16);
      W2lo[c * DD + tid] = (ushort_t)(pk & 0xffffu);
    }
  }
}

// ---------------------------------------------------------------------------
// Main fused kernel: 512 persistent blocks (8 waves) x WPB=4 windows each.
//  - W2 fragments loaded ONCE into registers (128 VGPR): P4 has zero global
//    loads in steady state.
//  - Gather for window i+1 issued right after barrier1 of window i: its L2
//    latency hides under P4's LDS+MFMA work.
//  - Pool contributions accumulated in regs across windows; one atomic/block.
// Per window:
//  P2: perm prefetched gather regs -> B-frags, attention MFMA (A = At split).
//  P3: tanh(+b1), split-pack -> H2 LDS (packed u32, rotation layout).
//  barrier; issue gather(win+1);
//  P4: matmul2 MFMA (A-frags from H2 via 2x ds_read_b128 + perms, B = regs).
//  P5: tanh(+b2) accumulated into pacc. barrier (H2 reuse).
// H2 rotation layout (verified conflict-free, see R5): p = (d + 4*t) & 255.
// ---------------------------------------------------------------------------
__global__ __launch_bounds__(512, 2) void main_kernel(
    const int*      __restrict__ x,    const uint_t* __restrict__ gpk,
    const ushort_t* __restrict__ Athi, const ushort_t* __restrict__ Atlo,
    const float*    __restrict__ b1,
    const ushort_t* __restrict__ W2hi, const ushort_t* __restrict__ W2lo,
    const float*    __restrict__ b2,   float* __restrict__ pool)
{
  __shared__ uint_t H2[WIN][DD];   // 64 KiB packed (hi<<16|lo), rotation layout

  const int tid  = threadIdx.x;
  const int lane = tid & 63;
  const int w    = tid >> 6;       // 0..7
  const int quad = lane >> 4;
  const int l16  = lane & 15;
  const int b   = blockIdx.x >> 4;        // 0..31
  const int grp = blockIdx.x & (NGRP-1);  // 0..15
  const int n0  = grp * WPB;

  const int dbase = 32 * w;        // this wave's d-slice (P2) == c-slice (P4)
  const int cbase = dbase;

  // --- persistent W2 fragments: 32 frags = 128 VGPR, loaded once ---
  short8 w2h[8][2], w2l[8][2];
  #pragma unroll
  for (int k0 = 0; k0 < 8; ++k0) {
    const int dsl = k0 * 32 + quad * 8;
    #pragma unroll
    for (int nt = 0; nt < 2; ++nt) {
      const int c = cbase + 16 * nt + l16;
      w2h[k0][nt] = *(const short8*)(W2hi + c * DD + dsl);
      w2l[k0][nt] = *(const short8*)(W2lo + c * DD + dsl);
    }
  }

  // hoisted biases
  float b1v[2], b2v[2];
  #pragma unroll
  for (int nt = 0; nt < 2; ++nt) {
    b1v[nt] = b1[dbase + 16 * nt + l16];
    b2v[nt] = b2[cbase + 16 * nt + l16];
  }

  float pacc[2] = {0.0f, 0.0f};    // pooled tanh sums for this block's windows

  // initial gather (window 0)
  uint_t q[2][2][8];
  int xvcur = x[b * SS + n0 * WIN + lane];
  issue_gather(gpk, xvcur, dbase, quad, l16, q);

  #pragma unroll 1
  for (int win = 0; win < WPB; ++win) {
    // early-issue next window's x (L1/L2 hit)
    int xvn = 0;
    if (win + 1 < WPB) xvn = x[b * SS + (n0 + win + 1) * WIN + lane];

    // --- P2: attention MFMA (consume prefetched q) ---
    f32x4 acc1[4][2];
    #pragma unroll
    for (int mt = 0; mt < 4; ++mt)
      #pragma unroll
      for (int nt = 0; nt < 2; ++nt) acc1[mt][nt] = (f32x4)0.0f;

    #pragma unroll
    for (int k0 = 0; k0 < 2; ++k0) {
      const int sl = k0 * 32 + quad * 8;
      short8 ah[4], al[4];
      #pragma unroll
      for (int mt = 0; mt < 4; ++mt) {
        const int t = mt * 16 + l16;
        ah[mt] = *(const short8*)(Athi + t * WIN + sl);   // L1-resident
        al[mt] = *(const short8*)(Atlo + t * WIN + sl);
      }
      short8 bh[2], bl[2];
      #pragma unroll
      for (int nt = 0; nt < 2; ++nt) {
        u4s8 h, l;
        #pragma unroll
        for (int p = 0; p < 4; ++p) {
          h.u[p] = perm_hi(q[k0][nt][2 * p], q[k0][nt][2 * p + 1]);
          l.u[p] = perm_lo(q[k0][nt][2 * p], q[k0][nt][2 * p + 1]);
        }
        bh[nt] = h.v;
        bl[nt] = l.v;
      }
      #pragma unroll
      for (int mt = 0; mt < 4; ++mt)
        #pragma unroll
        for (int nt = 0; nt < 2; ++nt) {
          acc1[mt][nt] = __builtin_amdgcn_mfma_f32_16x16x32_bf16(ah[mt], bh[nt], acc1[mt][nt], 0, 0, 0);
          acc1[mt][nt] = __builtin_amdgcn_mfma_f32_16x16x32_bf16(ah[mt], bl[nt], acc1[mt][nt], 0, 0, 0);
          acc1[mt][nt] = __builtin_amdgcn_mfma_f32_16x16x32_bf16(al[mt], bh[nt], acc1[mt][nt], 0, 0, 0);
        }
    }

    // --- P3: tanh(+b1), split, rotated write (2 lanes/bank = free) ---
    #pragma unroll
    for (int nt = 0; nt < 2; ++nt) {
      const int d = dbase + 16 * nt + l16;
      #pragma unroll
      for (int mt = 0; mt < 4; ++mt)
        #pragma unroll
        for (int r = 0; r < 4; ++r) {
          const int t = mt * 16 + quad * 4 + r;
          float h = fast_tanh(acc1[mt][nt][r] + b1v[nt]);
          H2[t][(d + 4 * t) & 255] = split_pack(h);
        }
    }
    __syncthreads();

    // --- prefetch gather for next window: flies during P4 ---
    if (win + 1 < WPB) issue_gather(gpk, xvn, dbase, quad, l16, q);
    xvcur = xvn;

    // --- P4: matmul2 MFMA, W2 from registers, A-frags from H2 ---
    f32x4 acc2[4][2];
    #pragma unroll
    for (int mt = 0; mt < 4; ++mt)
      #pragma unroll
      for (int nt = 0; nt < 2; ++nt) acc2[mt][nt] = (f32x4)0.0f;

    #pragma unroll 2
    for (int k0 = 0; k0 < 8; ++k0) {
      const int dsl = k0 * 32 + quad * 8;
      short8 ah[4], al[4];
      #pragma unroll
      for (int mt = 0; mt < 4; ++mt) {
        const int t = mt * 16 + l16;
        const uint_t* row = &H2[t][0];
        const int p0 = (dsl + 4 * t) & 255;
        const int p4 = (dsl + 4 + 4 * t) & 255;
        uint_t qq[8];
        *(uint4*)(qq)     = *(const uint4*)(row + p0);   // ds_read_b128
        *(uint4*)(qq + 4) = *(const uint4*)(row + p4);   // ds_read_b128
        u4s8 h, l;
        #pragma unroll
        for (int p = 0; p < 4; ++p) {
          h.u[p] = perm_hi(qq[2 * p], qq[2 * p + 1]);
          l.u[p] = perm_lo(qq[2 * p], qq[2 * p + 1]);
        }
        ah[mt] = h.v;
        al[mt] = l.v;
      }
      #pragma unroll
      for (int mt = 0; mt < 4; ++mt)
        #pragma unroll
        for (int nt = 0; nt < 2; ++nt) {
          acc2[mt][nt] = __builtin_amdgcn_mfma_f32_16x16x32_bf16(ah[mt], w2h[k0][nt], acc2[mt][nt], 0, 0, 0);
          acc2[mt][nt] = __builtin_amdgcn_mfma_f32_16x16x32_bf16(ah[mt], w2l[k0][nt], acc2[mt][nt], 0, 0, 0);
          acc2[mt][nt] = __builtin_amdgcn_mfma_f32_16x16x32_bf16(al[mt], w2h[k0][nt], acc2[mt][nt], 0, 0, 0);
        }
    }

    // --- P5: tanh(+b2) accumulate into pacc ---
    #pragma unroll
    for (int nt = 0; nt < 2; ++nt) {
      float p = 0.0f;
      #pragma unroll
      for (int mt = 0; mt < 4; ++mt)
        #pragma unroll
        for (int r = 0; r < 4; ++r)
          p += fast_tanh(acc2[mt][nt][r] + b2v[nt]);
      pacc[nt] += p;
    }

    if (win + 1 < WPB) __syncthreads();   // H2 safe to overwrite next window
  }

  // --- block epilogue: reduce over quads, one atomic per (b,c) ---
  #pragma unroll
  for (int nt = 0; nt < 2; ++nt) {
    float p = pacc[nt];
    p += __shfl_xor(p, 16, 64);
    p += __shfl_xor(p, 32, 64);
    if (quad == 0) atomicAdd(&pool[b * DD + cbase + 16 * nt + l16], p);
  }
}

// ---------------------------------------------------------------------------
// Final: out[b,c] = (pool[b,:] / S) . Wc[c,:] + bc[c]
// ---------------------------------------------------------------------------
__global__ __launch_bounds__(64) void final_kernel(
    const float* __restrict__ pool, const float* __restrict__ Wc,
    const float* __restrict__ bc, float* __restrict__ out)
{
  const int tid = threadIdx.x;
  if (tid < BB * CC) {
    const int b = tid / CC, c = tid % CC;
    const float* p = pool + b * DD;
    const float* wv = Wc + c * DD;
    float acc = 0.0f;
    #pragma unroll 4
    for (int d = 0; d < DD; ++d) acc += p[d] * wv[d];
    out[tid] = acc * (1.0f / 4096.0f) + bc[c];
  }
}

extern "C" void kernel_launch(void* const* d_in, const int* in_sizes, int n_in,
                              void* d_out, int out_size, void* d_ws, size_t ws_size,
                              hipStream_t stream) {
  const int*   x   = (const int*)  d_in[0];
  const float* emb = (const float*)d_in[1];
  const float* W1  = (const float*)d_in[2];
  const float* b1  = (const float*)d_in[3];
  const float* W2  = (const float*)d_in[4];
  const float* b2  = (const float*)d_in[5];
  const float* Wc  = (const float*)d_in[6];
  const float* bc  = (const float*)d_in[7];
  float* out = (float*)d_out;
  char*  ws  = (char*)d_ws;

  prep_kernel<<<130, 256, 0, stream>>>(emb, W1, W2, ws);
  main_kernel<<<BB * NGRP, 512, 0, stream>>>(
      x,
      (const uint_t*)  (ws + WS_GPK_B),
      (const ushort_t*)(ws + WS_ATHI_B), (const ushort_t*)(ws + WS_ATLO_B),
      b1,
      (const ushort_t*)(ws + WS_W2HI_B), (const ushort_t*)(ws + WS_W2LO_B),
      b2,
      (float*)(ws + WS_POOL_B));
  final_kernel<<<1, 64, 0, stream>>>((const float*)(ws + WS_POOL_B), Wc, bc, out);
}

// Round 7
// 240.858 us; speedup vs baseline: 1.0014x; 1.0014x over previous
//
#include <hip/hip_runtime.h>
#include <hip/hip_bf16.h>
#include <math.h>

// Problem constants (match reference)
#define BB  32
#define SS  4096
#define VV  256
#define DD  256
#define CC  2
#define WIN 64
#define NW  64   // SS/WIN
#define WPB 4    // windows per main block
#define NGRP (NW / WPB)   // 16 groups

typedef unsigned short ushort_t;
typedef unsigned int   uint_t;
typedef __attribute__((ext_vector_type(8))) short short8;    // 8 bf16 (4 VGPRs)
typedef __attribute__((ext_vector_type(4))) float f32x4;

// Workspace layout (byte offsets). Total 573440 B.
#define WS_ATHI_B 0u          // ushort Athi[64][64]   8192  (A-op layout: [t][s])
#define WS_ATLO_B 8192u       // ushort Atlo[64][64]   8192
#define WS_GPK_B  16384u      // uint   gpk[256][256]  262144 (hi<<16 | lo per elem)
#define WS_W2HI_B 278528u     // ushort W2hi[256][256] 131072
#define WS_W2LO_B 409600u     // ushort W2lo[256][256] 131072
#define WS_POOL_B 540672u     // float  pool[32][256]  32768

__device__ __forceinline__ float fast_tanh(float v) {
  float e = __expf(2.0f * v);
  return 1.0f - __fdividef(2.0f, e + 1.0f);
}

// Truncation-based bf16 split: v ~= hi + lo with |err| <= 2^-17 * |v|.
__device__ __forceinline__ uint_t split_pack(float v) {
  uint_t b  = __float_as_uint(v);
  uint_t hi = b & 0xffff0000u;
  float  r  = v - __uint_as_float(hi);
  uint_t lo = __float_as_uint(r) >> 16;
  return hi | lo;
}

// Pack hi/lo halves of two packed u32 into bf16 pair dwords via v_perm.
__device__ __forceinline__ uint_t perm_hi(uint_t p0, uint_t p1) {
  return __builtin_amdgcn_perm(p1, p0, 0x07060302u);
}
__device__ __forceinline__ uint_t perm_lo(uint_t p0, uint_t p1) {
  return __builtin_amdgcn_perm(p1, p0, 0x05040100u);
}

union u4s8 { uint_t u[4]; short8 v; };

// Issue the 32 gather loads for one window into raw packed regs q[k0][nt][j].
__device__ __forceinline__ void issue_gather(
    const uint_t* __restrict__ gpk, int xvw, int dbase, int quad, int l16,
    uint_t (&q)[2][2][8])
{
  #pragma unroll
  for (int k0 = 0; k0 < 2; ++k0) {
    const int sl = k0 * 32 + quad * 8;
    int xs[8];
    #pragma unroll
    for (int j = 0; j < 8; ++j) xs[j] = __shfl(xvw, sl + j, 64);
    #pragma unroll
    for (int nt = 0; nt < 2; ++nt) {
      const int d = dbase + 16 * nt + l16;
      #pragma unroll
      for (int j = 0; j < 8; ++j) q[k0][nt][j] = gpk[xs[j] * DD + d];
    }
  }
}

// ---------------------------------------------------------------------------
// Prep grid (1090 blocks):
//  blk 0          : attention matrix -> split bf16 planes Athi/Atlo ([t][s])
//  blk 1          : zero pooled accumulator
//  blk 2..1025    : g = emb @ W1^T. Block = (16 d-cols) x (4 v-rows); thread =
//                   (d, k-strip of 16) -> W1 reads fully coalesced; partial
//                   sums reduced via padded LDS.
//  blk 1026..1089 : W2 -> split planes W2hi/W2lo, 4 c-rows per block
// ---------------------------------------------------------------------------
__global__ __launch_bounds__(256) void prep_kernel(
    const float* __restrict__ emb, const float* __restrict__ W1,
    const float* __restrict__ W2, char* __restrict__ ws)
{
  const int blk = blockIdx.x;
  const int tid = threadIdx.x;
  ushort_t* Athi = (ushort_t*)(ws + WS_ATHI_B);
  ushort_t* Atlo = (ushort_t*)(ws + WS_ATLO_B);
  uint_t*   gpk  = (uint_t*)  (ws + WS_GPK_B);
  ushort_t* W2hi = (ushort_t*)(ws + WS_W2HI_B);
  ushort_t* W2lo = (ushort_t*)(ws + WS_W2LO_B);
  float*    pool = (float*)   (ws + WS_POOL_B);

  if (blk == 0) {
    if (tid < WIN) {
      const int s = tid;
      const float omega = 60.0f * 2.0f * 3.14159265358979323846f / 4095.0f;
      float row[WIN];
      float sum = 0.0f;
      for (int t = 0; t < WIN; ++t) {
        float e = expf(cosf(omega * (float)(s - t)));
        row[t] = e;
        sum += e;
      }
      const float inv = 1.0f / sum;
      for (int t = 0; t < WIN; ++t) {
        uint_t pk = split_pack(row[t] * inv);
        Athi[t * WIN + s] = (ushort_t)(pk >> 16);
        Atlo[t * WIN + s] = (ushort_t)(pk & 0xffffu);
      }
    }
  } else if (blk == 1) {
    for (int i = tid; i < BB * DD; i += 256) pool[i] = 0.0f;
  } else if (blk < 1026) {
    const int gv = blk - 2;            // 0..1023
    const int d0 = (gv & 15) * 16;     // 16 d-columns
    const int v0 = (gv >> 4) * 4;      // 4 v-rows
    __shared__ float er[4 * DD];       // 4 KB
    __shared__ float ps[4][16][17];    // padded partials
    *(float4*)(er + tid * 4) = *(const float4*)(emb + v0 * DD + tid * 4);
    __syncthreads();
    const int kq = tid & 15;           // k-strip: [16kq, 16kq+16)
    const int dl = tid >> 4;           // 0..15
    const int d  = d0 + dl;
    float4 wv[4];
    #pragma unroll
    for (int j = 0; j < 4; ++j)
      wv[j] = *(const float4*)(W1 + d * DD + 16 * kq + 4 * j);  // coalesced
    #pragma unroll
    for (int v = 0; v < 4; ++v) {
      float a = 0.0f;
      #pragma unroll
      for (int j = 0; j < 4; ++j) {
        float4 e = *(const float4*)(er + v * DD + 16 * kq + 4 * j);
        a += e.x * wv[j].x + e.y * wv[j].y + e.z * wv[j].z + e.w * wv[j].w;
      }
      ps[v][dl][kq] = a;
    }
    __syncthreads();
    if (tid < 64) {
      const int v = tid >> 4, dr = tid & 15;
      float s = 0.0f;
      #pragma unroll
      for (int k = 0; k < 16; ++k) s += ps[v][dr][k];
      gpk[(v0 + v) * DD + d0 + dr] = split_pack(s);
    }
  } else {
    const int c0 = (blk - 1026) * 4;
    #pragma unroll
    for (int i = 0; i < 4; ++i) {
      const int c = c0 + i;
      uint_t pk = split_pack(W2[c * DD + tid]);
      W2hi[c * DD + tid] = (ushort_t)(pk >> 16);
      W2lo[c * DD + tid] = (ushort_t)(pk & 0xffffu);
    }
  }
}

// ---------------------------------------------------------------------------
// Main fused kernel: 512 blocks (8 waves) x WPB=4 windows, gather-prefetched.
// Per window:
//  P2: perm prefetched gather regs -> B-frags, attention MFMA (A = At split).
//  P3: tanh(+b1), split-pack -> H2 LDS (packed u32, rotation layout).
//  barrier; issue gather(win+1) (L2 latency hides under P4);
//  P4: matmul2 MFMA, mt-at-a-time (A-frags: 2x ds_read_b128 + 8 perms; B: W2
//      planes from L2 per k0 — NOT register-persistent, see R6 spill).
//  P5: tanh(+b2) accumulated into pacc; barrier.
// Epilogue: shfl-reduce pacc over quads, one atomicAdd per (b,c).
// H2 rotation layout (verified conflict-free R5): p = (d + 4*t) & 255.
// ---------------------------------------------------------------------------
__global__ __launch_bounds__(512, 4) void main_kernel(
    const int*      __restrict__ x,    const uint_t* __restrict__ gpk,
    const ushort_t* __restrict__ Athi, const ushort_t* __restrict__ Atlo,
    const float*    __restrict__ b1,
    const ushort_t* __restrict__ W2hi, const ushort_t* __restrict__ W2lo,
    const float*    __restrict__ b2,   float* __restrict__ pool)
{
  __shared__ uint_t H2[WIN][DD];   // 64 KiB packed (hi<<16|lo), rotation layout

  const int tid  = threadIdx.x;
  const int lane = tid & 63;
  const int w    = tid >> 6;       // 0..7
  const int quad = lane >> 4;
  const int l16  = lane & 15;
  const int b   = blockIdx.x >> 4;        // 0..31
  const int grp = blockIdx.x & (NGRP-1);  // 0..15
  const int n0  = grp * WPB;

  const int dbase = 32 * w;        // this wave's d-slice (P2) == c-slice (P4)
  const int cbase = dbase;

  // preload all window token ids (4 VGPR)
  int xv[WPB];
  #pragma unroll
  for (int i = 0; i < WPB; ++i) xv[i] = x[b * SS + (n0 + i) * WIN + lane];

  // hoisted biases
  float b1v[2], b2v[2];
  #pragma unroll
  for (int nt = 0; nt < 2; ++nt) {
    b1v[nt] = b1[dbase + 16 * nt + l16];
    b2v[nt] = b2[cbase + 16 * nt + l16];
  }

  float pacc[2] = {0.0f, 0.0f};

  uint_t q[2][2][8];               // prefetched gather (32 VGPR)
  issue_gather(gpk, xv[0], dbase, quad, l16, q);

  #pragma unroll
  for (int win = 0; win < WPB; ++win) {
    // --- P2: attention MFMA (consume prefetched q) ---
    f32x4 acc1[4][2];
    #pragma unroll
    for (int mt = 0; mt < 4; ++mt)
      #pragma unroll
      for (int nt = 0; nt < 2; ++nt) acc1[mt][nt] = (f32x4)0.0f;

    #pragma unroll
    for (int k0 = 0; k0 < 2; ++k0) {
      const int sl = k0 * 32 + quad * 8;
      short8 bh[2], bl[2];
      #pragma unroll
      for (int nt = 0; nt < 2; ++nt) {
        u4s8 h, l;
        #pragma unroll
        for (int p = 0; p < 4; ++p) {
          h.u[p] = perm_hi(q[k0][nt][2 * p], q[k0][nt][2 * p + 1]);
          l.u[p] = perm_lo(q[k0][nt][2 * p], q[k0][nt][2 * p + 1]);
        }
        bh[nt] = h.v;
        bl[nt] = l.v;
      }
      #pragma unroll
      for (int mt = 0; mt < 4; ++mt) {
        const int t = mt * 16 + l16;
        short8 ah = *(const short8*)(Athi + t * WIN + sl);   // L1-resident
        short8 al = *(const short8*)(Atlo + t * WIN + sl);
        #pragma unroll
        for (int nt = 0; nt < 2; ++nt) {
          acc1[mt][nt] = __builtin_amdgcn_mfma_f32_16x16x32_bf16(ah, bh[nt], acc1[mt][nt], 0, 0, 0);
          acc1[mt][nt] = __builtin_amdgcn_mfma_f32_16x16x32_bf16(ah, bl[nt], acc1[mt][nt], 0, 0, 0);
          acc1[mt][nt] = __builtin_amdgcn_mfma_f32_16x16x32_bf16(al, bh[nt], acc1[mt][nt], 0, 0, 0);
        }
      }
    }

    // --- P3: tanh(+b1), split, rotated write (2 lanes/bank = free) ---
    #pragma unroll
    for (int nt = 0; nt < 2; ++nt) {
      const int d = dbase + 16 * nt + l16;
      #pragma unroll
      for (int mt = 0; mt < 4; ++mt)
        #pragma unroll
        for (int r = 0; r < 4; ++r) {
          const int t = mt * 16 + quad * 4 + r;
          float h = fast_tanh(acc1[mt][nt][r] + b1v[nt]);
          H2[t][(d + 4 * t) & 255] = split_pack(h);
        }
    }
    __syncthreads();

    // --- prefetch next window's gather: L2 latency hides under P4 ---
    if (win + 1 < WPB) issue_gather(gpk, xv[win + 1], dbase, quad, l16, q);

    // --- P4: matmul2 MFMA, mt-at-a-time (low reg pressure) ---
    f32x4 acc2[4][2];
    #pragma unroll
    for (int mt = 0; mt < 4; ++mt)
      #pragma unroll
      for (int nt = 0; nt < 2; ++nt) acc2[mt][nt] = (f32x4)0.0f;

    #pragma unroll 2
    for (int k0 = 0; k0 < 8; ++k0) {
      const int dsl = k0 * 32 + quad * 8;
      short8 wh[2], wl[2];
      #pragma unroll
      for (int nt = 0; nt < 2; ++nt) {
        const int c = cbase + 16 * nt + l16;
        wh[nt] = *(const short8*)(W2hi + c * DD + dsl);   // global dwordx4 (L2)
        wl[nt] = *(const short8*)(W2lo + c * DD + dsl);
      }
      #pragma unroll
      for (int mt = 0; mt < 4; ++mt) {
        const int t = mt * 16 + l16;
        const uint_t* row = &H2[t][0];
        const int p0 = (dsl + 4 * t) & 255;
        const int p4 = (dsl + 4 + 4 * t) & 255;
        uint_t qq[8];
        *(uint4*)(qq)     = *(const uint4*)(row + p0);   // ds_read_b128
        *(uint4*)(qq + 4) = *(const uint4*)(row + p4);   // ds_read_b128
        u4s8 h, l;
        #pragma unroll
        for (int p = 0; p < 4; ++p) {
          h.u[p] = perm_hi(qq[2 * p], qq[2 * p + 1]);
          l.u[p] = perm_lo(qq[2 * p], qq[2 * p + 1]);
        }
        short8 ah = h.v, al = l.v;
        #pragma unroll
        for (int nt = 0; nt < 2; ++nt) {
          acc2[mt][nt] = __builtin_amdgcn_mfma_f32_16x16x32_bf16(ah, wh[nt], acc2[mt][nt], 0, 0, 0);
          acc2[mt][nt] = __builtin_amdgcn_mfma_f32_16x16x32_bf16(ah, wl[nt], acc2[mt][nt], 0, 0, 0);
          acc2[mt][nt] = __builtin_amdgcn_mfma_f32_16x16x32_bf16(al, wh[nt], acc2[mt][nt], 0, 0, 0);
        }
      }
    }

    // --- P5: tanh(+b2) accumulate ---
    #pragma unroll
    for (int nt = 0; nt < 2; ++nt) {
      float p = 0.0f;
      #pragma unroll
      for (int mt = 0; mt < 4; ++mt)
        #pragma unroll
        for (int r = 0; r < 4; ++r)
          p += fast_tanh(acc2[mt][nt][r] + b2v[nt]);
      pacc[nt] += p;
    }

    if (win + 1 < WPB) __syncthreads();   // H2 safe to overwrite
  }

  // --- epilogue: reduce over quads, one atomic per (b,c) ---
  #pragma unroll
  for (int nt = 0; nt < 2; ++nt) {
    float p = pacc[nt];
    p += __shfl_xor(p, 16, 64);
    p += __shfl_xor(p, 32, 64);
    if (quad == 0) atomicAdd(&pool[b * DD + cbase + 16 * nt + l16], p);
  }
}

// ---------------------------------------------------------------------------
// Final: out[b,c] = (pool[b,:] / S) . Wc[c,:] + bc[c].  One block per b.
// ---------------------------------------------------------------------------
__global__ __launch_bounds__(64) void final_kernel(
    const float* __restrict__ pool, const float* __restrict__ Wc,
    const float* __restrict__ bc, float* __restrict__ out)
{
  const int b = blockIdx.x;
  const int t = threadIdx.x;
  float p0 = 0.0f, p1 = 0.0f;
  #pragma unroll
  for (int j = 0; j < 4; ++j) {
    float pv = pool[b * DD + t + 64 * j];
    p0 += pv * Wc[t + 64 * j];
    p1 += pv * Wc[DD + t + 64 * j];
  }
  #pragma unroll
  for (int off = 32; off; off >>= 1) {
    p0 += __shfl_xor(p0, off, 64);
    p1 += __shfl_xor(p1, off, 64);
  }
  if (t == 0) {
    out[b * CC + 0] = p0 * (1.0f / SS) + bc[0];
    out[b * CC + 1] = p1 * (1.0f / SS) + bc[1];
  }
}

extern "C" void kernel_launch(void* const* d_in, const int* in_sizes, int n_in,
                              void* d_out, int out_size, void* d_ws, size_t ws_size,
                              hipStream_t stream) {
  const int*   x   = (const int*)  d_in[0];
  const float* emb = (const float*)d_in[1];
  const float* W1  = (const float*)d_in[2];
  const float* b1  = (const float*)d_in[3];
  const float* W2  = (const float*)d_in[4];
  const float* b2  = (const float*)d_in[5];
  const float* Wc  = (const float*)d_in[6];
  const float* bc  = (const float*)d_in[7];
  float* out = (float*)d_out;
  char*  ws  = (char*)d_ws;

  prep_kernel<<<1090, 256, 0, stream>>>(emb, W1, W2, ws);
  main_kernel<<<BB * NGRP, 512, 0, stream>>>(
      x,
      (const uint_t*)  (ws + WS_GPK_B),
      (const ushort_t*)(ws + WS_ATHI_B), (const ushort_t*)(ws + WS_ATLO_B),
      b1,
      (const ushort_t*)(ws + WS_W2HI_B), (const ushort_t*)(ws + WS_W2LO_B),
      b2,
      (float*)(ws + WS_POOL_B));
  final_kernel<<<BB, 64, 0, stream>>>((const float*)(ws + WS_POOL_B), Wc, bc, out);
}

// Round 8
// 182.868 us; speedup vs baseline: 1.3190x; 1.3171x over previous
//
#include <hip/hip_runtime.h>
#include <hip/hip_bf16.h>
#include <math.h>

// Problem constants (match reference)
#define BB  32
#define SS  4096
#define VV  256
#define DD  256
#define CC  2
#define WIN 64
#define NW  64   // SS/WIN

typedef unsigned short ushort_t;
typedef unsigned int   uint_t;
typedef __attribute__((ext_vector_type(8))) short short8;    // 8 bf16 (4 VGPRs)
typedef __attribute__((ext_vector_type(4))) float f32x4;

// Workspace layout (byte offsets). Total 573440 B.
#define WS_ATHI_B 0u          // ushort Athi[64][64]   8192  (A-op layout: [t][s])
#define WS_ATLO_B 8192u       // ushort Atlo[64][64]   8192
#define WS_GPK_B  16384u      // uint   gpk[256][256]  262144 (hi<<16 | lo per elem)
#define WS_W2HI_B 278528u     // ushort W2hi[256][256] 131072
#define WS_W2LO_B 409600u     // ushort W2lo[256][256] 131072
#define WS_POOL_B 540672u     // float  pool[32][256]  32768

#define HP 264    // H2 plane row stride in shorts (256 + 8 pad)

__device__ __forceinline__ float fast_tanh(float v) {
  float e = __expf(2.0f * v);
  return 1.0f - __fdividef(2.0f, e + 1.0f);
}

// Truncation-based bf16 split: v ~= hi + lo with |err| <= 2^-17 * |v|.
__device__ __forceinline__ uint_t split_pack(float v) {
  uint_t b  = __float_as_uint(v);
  uint_t hi = b & 0xffff0000u;
  float  r  = v - __uint_as_float(hi);
  uint_t lo = __float_as_uint(r) >> 16;
  return hi | lo;
}

// Pack hi/lo halves of two packed u32 into bf16 pair dwords via v_perm.
__device__ __forceinline__ uint_t perm_hi(uint_t p0, uint_t p1) {
  return __builtin_amdgcn_perm(p1, p0, 0x07060302u);
}
__device__ __forceinline__ uint_t perm_lo(uint_t p0, uint_t p1) {
  return __builtin_amdgcn_perm(p1, p0, 0x05040100u);
}

union u4s8 { uint_t u[4]; short8 v; };

// ---------------------------------------------------------------------------
// Prep grid (1090 blocks):
//  blk 0          : attention matrix -> split bf16 planes Athi/Atlo ([t][s])
//  blk 1          : zero pooled accumulator
//  blk 2..1025    : g = emb @ W1^T (coalesced W1 reads, LDS partial reduce)
//  blk 1026..1089 : W2 -> split planes W2hi/W2lo, 4 c-rows per block
// ---------------------------------------------------------------------------
__global__ __launch_bounds__(256) void prep_kernel(
    const float* __restrict__ emb, const float* __restrict__ W1,
    const float* __restrict__ W2, char* __restrict__ ws)
{
  const int blk = blockIdx.x;
  const int tid = threadIdx.x;
  ushort_t* Athi = (ushort_t*)(ws + WS_ATHI_B);
  ushort_t* Atlo = (ushort_t*)(ws + WS_ATLO_B);
  uint_t*   gpk  = (uint_t*)  (ws + WS_GPK_B);
  ushort_t* W2hi = (ushort_t*)(ws + WS_W2HI_B);
  ushort_t* W2lo = (ushort_t*)(ws + WS_W2LO_B);
  float*    pool = (float*)   (ws + WS_POOL_B);

  if (blk == 0) {
    if (tid < WIN) {
      const int s = tid;
      const float omega = 60.0f * 2.0f * 3.14159265358979323846f / 4095.0f;
      float row[WIN];
      float sum = 0.0f;
      for (int t = 0; t < WIN; ++t) {
        float e = expf(cosf(omega * (float)(s - t)));
        row[t] = e;
        sum += e;
      }
      const float inv = 1.0f / sum;
      for (int t = 0; t < WIN; ++t) {
        uint_t pk = split_pack(row[t] * inv);
        Athi[t * WIN + s] = (ushort_t)(pk >> 16);
        Atlo[t * WIN + s] = (ushort_t)(pk & 0xffffu);
      }
    }
  } else if (blk == 1) {
    for (int i = tid; i < BB * DD; i += 256) pool[i] = 0.0f;
  } else if (blk < 1026) {
    const int gv = blk - 2;            // 0..1023
    const int d0 = (gv & 15) * 16;     // 16 d-columns
    const int v0 = (gv >> 4) * 4;      // 4 v-rows
    __shared__ float er[4 * DD];       // 4 KB
    __shared__ float ps[4][16][17];    // padded partials
    *(float4*)(er + tid * 4) = *(const float4*)(emb + v0 * DD + tid * 4);
    __syncthreads();
    const int kq = tid & 15;           // k-strip: [16kq, 16kq+16)
    const int dl = tid >> 4;           // 0..15
    const int d  = d0 + dl;
    float4 wv[4];
    #pragma unroll
    for (int j = 0; j < 4; ++j)
      wv[j] = *(const float4*)(W1 + d * DD + 16 * kq + 4 * j);  // coalesced
    #pragma unroll
    for (int v = 0; v < 4; ++v) {
      float a = 0.0f;
      #pragma unroll
      for (int j = 0; j < 4; ++j) {
        float4 e = *(const float4*)(er + v * DD + 16 * kq + 4 * j);
        a += e.x * wv[j].x + e.y * wv[j].y + e.z * wv[j].z + e.w * wv[j].w;
      }
      ps[v][dl][kq] = a;
    }
    __syncthreads();
    if (tid < 64) {
      const int v = tid >> 4, dr = tid & 15;
      float s = 0.0f;
      #pragma unroll
      for (int k = 0; k < 16; ++k) s += ps[v][dr][k];
      gpk[(v0 + v) * DD + d0 + dr] = split_pack(s);
    }
  } else {
    const int c0 = (blk - 1026) * 4;
    #pragma unroll
    for (int i = 0; i < 4; ++i) {
      const int c = c0 + i;
      uint_t pk = split_pack(W2[c * DD + tid]);
      W2hi[c * DD + tid] = (ushort_t)(pk >> 16);
      W2lo[c * DD + tid] = (ushort_t)(pk & 0xffffu);
    }
  }
}

// ---------------------------------------------------------------------------
// Main fused kernel: one block (512 thr, 8 waves) per (batch b, window n).
// R5 shape (known spill-free) + two deltas:
//  (1) H2 stored as separate hi/lo ushort planes [64][264] -> P4 A-frags are
//      direct ds_read_b128, zero v_perm unpacks (R5 spent 256/window).
//      Pad 264: read bank = 4*(l16+quad)+j mod 32 -> 8 dwords/bank = exact
//      8-phase minimum, conflict-free. b16 writes ~2-phase.
//  (2) W2 fragments double-buffered across k0 (unroll 2, compile-time bufs):
//      k0+1's L2 loads fly under k0's MFMAs.
// ---------------------------------------------------------------------------
__global__ __launch_bounds__(512, 4) void main_kernel(
    const int*      __restrict__ x,    const uint_t* __restrict__ gpk,
    const ushort_t* __restrict__ Athi, const ushort_t* __restrict__ Atlo,
    const float*    __restrict__ b1,
    const ushort_t* __restrict__ W2hi, const ushort_t* __restrict__ W2lo,
    const float*    __restrict__ b2,   float* __restrict__ pool)
{
  __shared__ ushort_t Hhi[WIN][HP];   // 33792 B
  __shared__ ushort_t Hlo[WIN][HP];   // 33792 B (total 67584 -> 2 blocks/CU)

  const int tid  = threadIdx.x;
  const int lane = tid & 63;
  const int w    = tid >> 6;       // 0..7
  const int quad = lane >> 4;
  const int l16  = lane & 15;
  const int b = blockIdx.x >> 6;
  const int n = blockIdx.x & 63;

  const int dbase = 32 * w;        // this wave's d-slice (P2) == c-slice (P4)
  const int cbase = dbase;

  // --- P1: gather (packed u32), issued first so latency overlaps setup ---
  const int xv = x[b * SS + n * WIN + lane];
  uint_t q[2][2][8];
  #pragma unroll
  for (int k0 = 0; k0 < 2; ++k0) {
    const int sl = k0 * 32 + quad * 8;
    int xs[8];
    #pragma unroll
    for (int j = 0; j < 8; ++j) xs[j] = __shfl(xv, sl + j, 64);
    #pragma unroll
    for (int nt = 0; nt < 2; ++nt) {
      const int d = dbase + 16 * nt + l16;
      #pragma unroll
      for (int j = 0; j < 8; ++j) q[k0][nt][j] = gpk[xs[j] * DD + d];
    }
  }

  float b1v[2], b2v[2];
  #pragma unroll
  for (int nt = 0; nt < 2; ++nt) {
    b1v[nt] = b1[dbase + 16 * nt + l16];
    b2v[nt] = b2[cbase + 16 * nt + l16];
  }

  // --- P2: attention MFMA ---
  f32x4 acc1[4][2];
  #pragma unroll
  for (int mt = 0; mt < 4; ++mt)
    #pragma unroll
    for (int nt = 0; nt < 2; ++nt) acc1[mt][nt] = (f32x4)0.0f;

  #pragma unroll
  for (int k0 = 0; k0 < 2; ++k0) {
    const int sl = k0 * 32 + quad * 8;
    short8 bh[2], bl[2];
    #pragma unroll
    for (int nt = 0; nt < 2; ++nt) {
      u4s8 h, l;
      #pragma unroll
      for (int p = 0; p < 4; ++p) {
        h.u[p] = perm_hi(q[k0][nt][2 * p], q[k0][nt][2 * p + 1]);
        l.u[p] = perm_lo(q[k0][nt][2 * p], q[k0][nt][2 * p + 1]);
      }
      bh[nt] = h.v;
      bl[nt] = l.v;
    }
    #pragma unroll
    for (int mt = 0; mt < 4; ++mt) {
      const int t = mt * 16 + l16;
      short8 ah = *(const short8*)(Athi + t * WIN + sl);   // L1-resident
      short8 al = *(const short8*)(Atlo + t * WIN + sl);
      #pragma unroll
      for (int nt = 0; nt < 2; ++nt) {
        acc1[mt][nt] = __builtin_amdgcn_mfma_f32_16x16x32_bf16(ah, bh[nt], acc1[mt][nt], 0, 0, 0);
        acc1[mt][nt] = __builtin_amdgcn_mfma_f32_16x16x32_bf16(ah, bl[nt], acc1[mt][nt], 0, 0, 0);
        acc1[mt][nt] = __builtin_amdgcn_mfma_f32_16x16x32_bf16(al, bh[nt], acc1[mt][nt], 0, 0, 0);
      }
    }
  }

  // --- P3: tanh(+b1), split, store to hi/lo planes (b16, ~2-phase) ---
  #pragma unroll
  for (int nt = 0; nt < 2; ++nt) {
    const int d = dbase + 16 * nt + l16;
    #pragma unroll
    for (int mt = 0; mt < 4; ++mt)
      #pragma unroll
      for (int r = 0; r < 4; ++r) {
        const int t = mt * 16 + quad * 4 + r;
        float h = fast_tanh(acc1[mt][nt][r] + b1v[nt]);
        uint_t pk = split_pack(h);
        Hhi[t][d] = (ushort_t)(pk >> 16);
        Hlo[t][d] = (ushort_t)(pk & 0xffffu);
      }
  }
  __syncthreads();   // the only barrier

  // --- P4: matmul2 MFMA, W2 double-buffered, A-frags direct b128 ---
  f32x4 acc2[4][2];
  #pragma unroll
  for (int mt = 0; mt < 4; ++mt)
    #pragma unroll
    for (int nt = 0; nt < 2; ++nt) acc2[mt][nt] = (f32x4)0.0f;

  short8 wh[2][2], wl[2][2];
  {
    const int dsl0 = quad * 8;
    #pragma unroll
    for (int nt = 0; nt < 2; ++nt) {
      const int c = cbase + 16 * nt + l16;
      wh[0][nt] = *(const short8*)(W2hi + c * DD + dsl0);
      wl[0][nt] = *(const short8*)(W2lo + c * DD + dsl0);
    }
  }

  #pragma unroll 2
  for (int k0 = 0; k0 < 8; ++k0) {
    const int cur = k0 & 1, nxt = cur ^ 1;
    const int dsl = k0 * 32 + quad * 8;
    if (k0 < 7) {
      const int dsln = dsl + 32;
      #pragma unroll
      for (int nt = 0; nt < 2; ++nt) {
        const int c = cbase + 16 * nt + l16;
        wh[nxt][nt] = *(const short8*)(W2hi + c * DD + dsln);   // prefetch k0+1
        wl[nxt][nt] = *(const short8*)(W2lo + c * DD + dsln);
      }
    }
    #pragma unroll
    for (int mt = 0; mt < 4; ++mt) {
      const int t = mt * 16 + l16;
      short8 ah = *(const short8*)(&Hhi[t][dsl]);   // ds_read_b128, clean
      short8 al = *(const short8*)(&Hlo[t][dsl]);
      #pragma unroll
      for (int nt = 0; nt < 2; ++nt) {
        acc2[mt][nt] = __builtin_amdgcn_mfma_f32_16x16x32_bf16(ah, wh[cur][nt], acc2[mt][nt], 0, 0, 0);
        acc2[mt][nt] = __builtin_amdgcn_mfma_f32_16x16x32_bf16(ah, wl[cur][nt], acc2[mt][nt], 0, 0, 0);
        acc2[mt][nt] = __builtin_amdgcn_mfma_f32_16x16x32_bf16(al, wh[cur][nt], acc2[mt][nt], 0, 0, 0);
      }
    }
  }

  // --- P5: tanh(+b2) + token-sum, one atomic per (b,c) ---
  #pragma unroll
  for (int nt = 0; nt < 2; ++nt) {
    float p = 0.0f;
    #pragma unroll
    for (int mt = 0; mt < 4; ++mt)
      #pragma unroll
      for (int r = 0; r < 4; ++r)
        p += fast_tanh(acc2[mt][nt][r] + b2v[nt]);
    p += __shfl_xor(p, 16, 64);
    p += __shfl_xor(p, 32, 64);
    if (quad == 0) atomicAdd(&pool[b * DD + cbase + 16 * nt + l16], p);
  }
}

// ---------------------------------------------------------------------------
// Final: out[b,c] = (pool[b,:] / S) . Wc[c,:] + bc[c].  One block per b.
// ---------------------------------------------------------------------------
__global__ __launch_bounds__(64) void final_kernel(
    const float* __restrict__ pool, const float* __restrict__ Wc,
    const float* __restrict__ bc, float* __restrict__ out)
{
  const int b = blockIdx.x;
  const int t = threadIdx.x;
  float p0 = 0.0f, p1 = 0.0f;
  #pragma unroll
  for (int j = 0; j < 4; ++j) {
    float pv = pool[b * DD + t + 64 * j];
    p0 += pv * Wc[t + 64 * j];
    p1 += pv * Wc[DD + t + 64 * j];
  }
  #pragma unroll
  for (int off = 32; off; off >>= 1) {
    p0 += __shfl_xor(p0, off, 64);
    p1 += __shfl_xor(p1, off, 64);
  }
  if (t == 0) {
    out[b * CC + 0] = p0 * (1.0f / SS) + bc[0];
    out[b * CC + 1] = p1 * (1.0f / SS) + bc[1];
  }
}

extern "C" void kernel_launch(void* const* d_in, const int* in_sizes, int n_in,
                              void* d_out, int out_size, void* d_ws, size_t ws_size,
                              hipStream_t stream) {
  const int*   x   = (const int*)  d_in[0];
  const float* emb = (const float*)d_in[1];
  const float* W1  = (const float*)d_in[2];
  const float* b1  = (const float*)d_in[3];
  const float* W2  = (const float*)d_in[4];
  const float* b2  = (const float*)d_in[5];
  const float* Wc  = (const float*)d_in[6];
  const float* bc  = (const float*)d_in[7];
  float* out = (float*)d_out;
  char*  ws  = (char*)d_ws;

  prep_kernel<<<1090, 256, 0, stream>>>(emb, W1, W2, ws);
  main_kernel<<<BB * NW, 512, 0, stream>>>(
      x,
      (const uint_t*)  (ws + WS_GPK_B),
      (const ushort_t*)(ws + WS_ATHI_B), (const ushort_t*)(ws + WS_ATLO_B),
      b1,
      (const ushort_t*)(ws + WS_W2HI_B), (const ushort_t*)(ws + WS_W2LO_B),
      b2,
      (float*)(ws + WS_POOL_B));
  final_kernel<<<BB, 64, 0, stream>>>((const float*)(ws + WS_POOL_B), Wc, bc, out);
}